// Round 11
// baseline (390.028 us; speedup 1.0000x reference)
//
#include <hip/hip_runtime.h>
#include <hip/hip_bf16.h>

#define B_ 32
#define T_ 1024
#define C_ 768
#define H_ 12
#define D_ 64
#define BT_ (B_*T_)
#define CC_ (C_*C_)

typedef __attribute__((ext_vector_type(4))) float f32x4;
typedef __attribute__((ext_vector_type(8))) short bf16x8;
typedef __attribute__((ext_vector_type(4))) short short4_t;
typedef __attribute__((ext_vector_type(2))) unsigned int u32x2;
typedef unsigned short u16;
typedef unsigned int u32;

// Q pre-scale: 1/sqrt(64) * log2(e), so attention probs = exp2(score).
#define QSCALE 0.1803368801111244f

__device__ __forceinline__ float bf2f(u16 u){
  union { float f; unsigned int i; } v; v.i = ((unsigned int)u)<<16; return v.f;
}
__device__ __forceinline__ u16 f2bf(float f){
  union { float f; unsigned int i; } v; v.f = f;
  return (u16)((v.i + 0x7fffu + ((v.i>>16)&1u)) >> 16);
}
// pack two positive floats to bf16 pair (round-half-up), lo in bits[15:0]
__device__ __forceinline__ u32 pack2bf(float lo, float hi){
  union { float f; u32 i; } a, b; a.f = lo; b.f = hi;
  return ((a.i + 0x8000u) >> 16) | ((b.i + 0x8000u) & 0xFFFF0000u);
}
__device__ __forceinline__ void split2(float f, u16& h, u16& l){
  h = f2bf(f);
  l = f2bf(f - bf2f(h));
}

// global -> LDS direct copy, 16B per lane; LDS dest = base + lane*16 (linear).
__device__ __forceinline__ void gll16(const void* g, void* l){
  __builtin_amdgcn_global_load_lds(
      (const __attribute__((address_space(1))) u32*)g,
      (__attribute__((address_space(3))) u32*)l, 16, 0, 0);
}

__global__ void sentinel_kernel(float* out, int n){
  int i = blockIdx.x*blockDim.x + threadIdx.x;
  if (i < n) out[i] = 12345.0f;
}

// fp32 -> bf16, 8 elements/thread
__global__ void xquant_kernel(const float* __restrict__ x, u16* __restrict__ xb, int n8){
  int i = blockIdx.x*blockDim.x + threadIdx.x;
  int stride = gridDim.x*blockDim.x;
  for (; i < n8; i += stride) {
    f32x4 a = *(const f32x4*)(x + (size_t)i*8);
    f32x4 b = *(const f32x4*)(x + (size_t)i*8 + 4);
    bf16x8 o;
    #pragma unroll
    for (int j = 0; j < 4; ++j) { o[j] = (short)f2bf(a[j]); o[j+4] = (short)f2bf(b[j]); }
    *(bf16x8*)(xb + (size_t)i*8) = o;
  }
}

// One-shot weight prep: qw/kw/vw -> bf16 concat W3b; ow -> hi/lo split.
__global__ void wquant_kernel(const float* __restrict__ qw, const float* __restrict__ kw,
                              const float* __restrict__ vw, const float* __restrict__ ow,
                              u16* __restrict__ W3b, u16* __restrict__ Wohi,
                              u16* __restrict__ Wolo){
  int i = (blockIdx.x*blockDim.x + threadIdx.x)*4;
  if (i >= CC_) return;
  f32x4 q = *(const f32x4*)(qw+i);
  f32x4 k = *(const f32x4*)(kw+i);
  f32x4 v = *(const f32x4*)(vw+i);
  f32x4 o = *(const f32x4*)(ow+i);
  short4_t tq, tk, tv, th, tl;
  #pragma unroll
  for (int j = 0; j < 4; ++j) {
    tq[j] = (short)f2bf(q[j]);
    tk[j] = (short)f2bf(k[j]);
    tv[j] = (short)f2bf(v[j]);
    u16 hh, ll; split2(o[j], hh, ll);
    th[j] = (short)hh; tl[j] = (short)ll;
  }
  *(short4_t*)(W3b + i)          = tq;
  *(short4_t*)(W3b + CC_ + i)    = tk;
  *(short4_t*)(W3b + 2*CC_ + i)  = tv;
  *(short4_t*)(Wohi + i)         = th;
  *(short4_t*)(Wolo + i)         = tl;
}

// ---------------- QKV projection, 256x256 tile, phased schedule ----------------
// Same as r10 but WITHOUT the sched_barrier(0) order-pins (m141: pins cost 1.7x
// by defeating the compiler's fine-grained lgkmcnt interleave). Compiler is now
// free to overlap ds_reads of the next quadrant with current MFMA cluster.
// Grid 1152 = 8 XCDs x (16 mloc x 9 nb), n innermost -> W3b (3.5 MB) L2-resident.
__global__ __launch_bounds__(512,1)
void gemm_qkv(const u16* __restrict__ Ab, const u16* __restrict__ Wb,
              const float* __restrict__ bq, const float* __restrict__ bk,
              const float* __restrict__ bv,
              u16* __restrict__ Qb, u16* __restrict__ Kb, u16* __restrict__ Vb)
{
  __shared__ __align__(1024) u16 sA[2][256*64];
  __shared__ __align__(1024) u16 sB[2][256*64];
  const int tid = threadIdx.x;
  const int lane = tid & 63;
  const int l15 = lane & 15, l16 = lane >> 4;
  const int wave = tid >> 6;            // 0..7
  const int wm = wave >> 2, wn = wave & 3;
  const int bid = blockIdx.x;
  const int xcd = bid & 7;
  const int idx = bid >> 3;
  const int mloc = idx / 9, nb = idx % 9;
  const int m0 = (xcd*16 + mloc) * 256;
  const int n0 = nb * 256;
  const int z  = nb / 3;
  const float* bias = (z==0) ? bq : (z==1 ? bk : bv);

  const int lrow = lane >> 3;
  const int cbyte = ((lane & 7) ^ lrow) << 4;

  f32x4 acc[8][4];
  #pragma unroll
  for (int i=0;i<8;++i)
    #pragma unroll
    for (int j=0;j<4;++j)
      acc[i][j] = (f32x4){0.f,0.f,0.f,0.f};

  auto stageA = [&](int c, int kt){
    #pragma unroll
    for (int i=0;i<4;++i){
      int row = i*64 + wave*8 + lrow;
      gll16((const char*)(Ab + (size_t)(m0+row)*C_ + kt*64) + cbyte,
            sA[c] + (i*64 + wave*8)*64);
    }
  };
  auto stageB = [&](int c, int kt){
    #pragma unroll
    for (int i=0;i<4;++i){
      int row = i*64 + wave*8 + lrow;
      gll16((const char*)(Wb + (size_t)(n0+row)*C_ + kt*64) + cbyte,
            sB[c] + (i*64 + wave*8)*64);
    }
  };

  stageA(0,0); stageB(0,0);
  asm volatile("s_waitcnt vmcnt(0)" ::: "memory");
  __syncthreads();

  for (int t = 0; t < 12; ++t) {
    const int c = t & 1;
    const u16* Atile = sA[c];
    const u16* Btile = sB[c];
    bf16x8 aLo[4][2], aHi[4][2], bLo[2][2], bHi[2][2];

    // ---- P0: stage A(t+1); read aLo,bLo; MFMA quadrant (mLo x nLo) ----
    if (t < 11) stageA(c^1, t+1);
    #pragma unroll
    for (int mf=0; mf<4; ++mf)
      #pragma unroll
      for (int kc=0; kc<2; ++kc){
        int row = wm*128 + mf*16 + l15;
        aLo[mf][kc] = *(const bf16x8*)((const char*)Atile + row*128 + ((kc*64 + l16*16) ^ ((row&7)<<4)));
      }
    #pragma unroll
    for (int nf=0; nf<2; ++nf)
      #pragma unroll
      for (int kc=0; kc<2; ++kc){
        int row = wn*64 + nf*16 + l15;
        bLo[nf][kc] = *(const bf16x8*)((const char*)Btile + row*128 + ((kc*64 + l16*16) ^ ((row&7)<<4)));
      }
    __builtin_amdgcn_s_setprio(1);
    #pragma unroll
    for (int mf=0; mf<4; ++mf)
      #pragma unroll
      for (int nf=0; nf<2; ++nf)
        #pragma unroll
        for (int kc=0; kc<2; ++kc)
          acc[mf][nf] = __builtin_amdgcn_mfma_f32_16x16x32_bf16(aLo[mf][kc], bLo[nf][kc], acc[mf][nf],0,0,0);
    __builtin_amdgcn_s_setprio(0);

    // ---- P1: stage B(t+1); read bHi; MFMA (mLo x nHi) ----
    if (t < 11) stageB(c^1, t+1);
    #pragma unroll
    for (int nf=0; nf<2; ++nf)
      #pragma unroll
      for (int kc=0; kc<2; ++kc){
        int row = wn*64 + (nf+2)*16 + l15;
        bHi[nf][kc] = *(const bf16x8*)((const char*)Btile + row*128 + ((kc*64 + l16*16) ^ ((row&7)<<4)));
      }
    __builtin_amdgcn_s_setprio(1);
    #pragma unroll
    for (int mf=0; mf<4; ++mf)
      #pragma unroll
      for (int nf=0; nf<2; ++nf)
        #pragma unroll
        for (int kc=0; kc<2; ++kc)
          acc[mf][nf+2] = __builtin_amdgcn_mfma_f32_16x16x32_bf16(aLo[mf][kc], bHi[nf][kc], acc[mf][nf+2],0,0,0);
    __builtin_amdgcn_s_setprio(0);

    // ---- P2: read aHi; MFMA (mHi x nHi) ----
    #pragma unroll
    for (int mf=0; mf<4; ++mf)
      #pragma unroll
      for (int kc=0; kc<2; ++kc){
        int row = wm*128 + (mf+4)*16 + l15;
        aHi[mf][kc] = *(const bf16x8*)((const char*)Atile + row*128 + ((kc*64 + l16*16) ^ ((row&7)<<4)));
      }
    __builtin_amdgcn_s_setprio(1);
    #pragma unroll
    for (int mf=0; mf<4; ++mf)
      #pragma unroll
      for (int nf=0; nf<2; ++nf)
        #pragma unroll
        for (int kc=0; kc<2; ++kc)
          acc[mf+4][nf+2] = __builtin_amdgcn_mfma_f32_16x16x32_bf16(aHi[mf][kc], bHi[nf][kc], acc[mf+4][nf+2],0,0,0);
    __builtin_amdgcn_s_setprio(0);

    // ---- P3: MFMA (mHi x nLo); then drain staged loads, one barrier ----
    __builtin_amdgcn_s_setprio(1);
    #pragma unroll
    for (int mf=0; mf<4; ++mf)
      #pragma unroll
      for (int nf=0; nf<2; ++nf)
        #pragma unroll
        for (int kc=0; kc<2; ++kc)
          acc[mf+4][nf] = __builtin_amdgcn_mfma_f32_16x16x32_bf16(aHi[mf][kc], bLo[nf][kc], acc[mf+4][nf],0,0,0);
    __builtin_amdgcn_s_setprio(0);
    if (t < 11) {
      asm volatile("s_waitcnt vmcnt(0)" ::: "memory");
      __syncthreads();
    }
  }

  // ---- epilogue: same per-fragment scatter as the verified 128 kernel ----
  #pragma unroll
  for (int mf = 0; mf < 8; ++mf) {
    #pragma unroll
    for (int nf = 0; nf < 4; ++nf) {
      int mgb = m0 + wm*128 + mf*16 + l16*4;
      int ngz = (nb%3)*256 + wn*64 + nf*16 + l15;
      float bv = bias[ngz];
      int b = mgb >> 10, t0 = mgb & 1023;
      int h = ngz >> 6, d = ngz & 63;
      int bh_ = b*H_ + h;
      if (z == 2) {
        short4_t vh;
        #pragma unroll
        for (int r = 0; r < 4; ++r)
          vh[r] = (short)f2bf(acc[mf][nf][r] + bv);
        size_t idx2 = ((size_t)bh_*D_ + d)*T_ + t0;
        *(short4_t*)&Vb[idx2] = vh;
      } else {
        u16* dst = (z==0) ? Qb : Kb;
        float scale = (z==0) ? QSCALE : 1.0f;
        #pragma unroll
        for (int r = 0; r < 4; ++r) {
          size_t idx2 = ((size_t)bh_*T_ + (t0+r))*D_ + d;
          dst[idx2] = f2bf((acc[mf][nf][r] + bv) * scale);
        }
      }
    }
  }
}

// O-projection (unchanged r8 structure): A=AOb (exact bf16), W split hi/lo,
// 2 MFMA passes -> fp32 Out + bias. 128x128 tile, global_load_lds staging.
__global__ __launch_bounds__(256,2)
void gemm_out(const u16* __restrict__ Ab, const u16* __restrict__ Whi,
              const u16* __restrict__ Wlo_, const float* __restrict__ bo,
              float* __restrict__ Out)
{
  __shared__ __align__(1024) u16 sA[128*64];
  __shared__ __align__(1024) u16 sB[128*64];
  __shared__ __align__(1024) u16 sBl[128*64];
  const int tid = threadIdx.x;
  const int lane = tid & 63;
  const int l15 = lane & 15, l16 = lane >> 4;
  const int wave = tid >> 6;
  const int wr = wave >> 1, wc = wave & 1;

  const int bid = blockIdx.x;
  const int xcd = bid & 7;
  const int idx = bid >> 3;
  const int nb = idx % 6, mloc = idx / 6;
  const int m0 = (xcd*32 + mloc) * 128;
  const int n0 = nb * 128;

  const int lrow = lane >> 3;
  const int cbyte = ((lane & 7) ^ lrow) << 4;

  f32x4 acc[4][4];
  #pragma unroll
  for (int i=0;i<4;++i)
    #pragma unroll
    for (int j=0;j<4;++j)
      acc[i][j] = (f32x4){0.f,0.f,0.f,0.f};

  for (int k0 = 0; k0 < C_; k0 += 64) {
    __syncthreads();
    #pragma unroll
    for (int sg = 0; sg < 4; ++sg) {
      int seg = wave*4 + sg;
      int row = seg*8 + lrow;
      gll16((const char*)(Ab   + (size_t)(m0+row)*C_ + k0) + cbyte, sA  + seg*512);
      gll16((const char*)(Whi  + (size_t)(n0+row)*C_ + k0) + cbyte, sB  + seg*512);
      gll16((const char*)(Wlo_ + (size_t)(n0+row)*C_ + k0) + cbyte, sBl + seg*512);
    }
    asm volatile("s_waitcnt vmcnt(0)" ::: "memory");
    __syncthreads();

    #pragma unroll
    for (int kc = 0; kc < 2; ++kc) {
      bf16x8 a[4], bh[4], bl[4];
      #pragma unroll
      for (int mf = 0; mf < 4; ++mf) {
        int row = wr*64 + mf*16 + l15;
        int off = (row<<7) + ((kc*64 + l16*16) ^ ((row&7)<<4));
        a[mf] = *(const bf16x8*)((const char*)sA + off);
      }
      #pragma unroll
      for (int nf = 0; nf < 4; ++nf) {
        int row = wc*64 + nf*16 + l15;
        int off = (row<<7) + ((kc*64 + l16*16) ^ ((row&7)<<4));
        bh[nf] = *(const bf16x8*)((const char*)sB + off);
        bl[nf] = *(const bf16x8*)((const char*)sBl + off);
      }
      #pragma unroll
      for (int mf = 0; mf < 4; ++mf)
        #pragma unroll
        for (int nf = 0; nf < 4; ++nf) {
          acc[mf][nf] = __builtin_amdgcn_mfma_f32_16x16x32_bf16(a[mf], bh[nf], acc[mf][nf],0,0,0);
          acc[mf][nf] = __builtin_amdgcn_mfma_f32_16x16x32_bf16(a[mf], bl[nf], acc[mf][nf],0,0,0);
        }
    }
  }

  #pragma unroll
  for (int mf = 0; mf < 4; ++mf) {
    #pragma unroll
    for (int nf = 0; nf < 4; ++nf) {
      int mgb = m0 + wr*64 + mf*16 + l16*4;
      int ng  = n0 + wc*64 + nf*16 + l15;
      float bv = bo[ng];
      #pragma unroll
      for (int r = 0; r < 4; ++r)
        Out[(size_t)(mgb+r)*C_ + ng] = acc[mf][nf][r] + bv;
    }
  }
}

// Flash attention, no-max softmax. SWAPPED QK^T: s = mfma(K_frag, Q_frag) so
// lane holds P^T: q = lane&15, key = 16nf + (lane>>4)*4 + r. Rowsum is
// lane-local. P regroup via per-wave LDS bounce (8x ds_write_b64, swizzled).
// One workgroup = (b,h) x 128 q-rows; 4 waves x 32 rows (2 m-frags).
// T14 async-stage K/V via register prefetch. Grid 3072 XCD-swizzled.
__global__ __launch_bounds__(256,2)
void attn_kernel(const u16* __restrict__ Qb, const u16* __restrict__ Kb,
                 const u16* __restrict__ Vb, u16* __restrict__ AOb)
{
  __shared__ __align__(16) u16 sK[64*64];
  __shared__ __align__(16) u16 sV[64*64];   // [d][key]
  __shared__ __align__(16) u32 sP[4][32*32]; // per wave: [q 32][key-word 32]
  const int tid = threadIdx.x;
  const int lane = tid & 63;
  const int l15 = lane & 15, l16 = lane >> 4;
  const int wave = tid >> 6;
  const int bid = blockIdx.x;
  const int sw  = (bid & 7) * 384 + (bid >> 3);   // 3072 = 8 XCDs * 384
  const int bh  = sw >> 3;
  const int q0  = (sw & 7) * 128 + wave * 32;

  bf16x8 qh[2][2];
  #pragma unroll
  for (int mf = 0; mf < 2; ++mf)
    #pragma unroll
    for (int kc = 0; kc < 2; ++kc)
      qh[mf][kc] = *(const bf16x8*)(Qb + ((size_t)bh*T_ + q0 + mf*16 + l15)*D_ + kc*32 + l16*8);

  f32x4 o[2][4];
  #pragma unroll
  for (int mf = 0; mf < 2; ++mf)
    #pragma unroll
    for (int i = 0; i < 4; ++i) o[mf][i] = (f32x4){0.f,0.f,0.f,0.f};
  float l_r[2] = {0.f, 0.f};

  const size_t kbase = (size_t)bh * (T_*D_);
  const size_t vbase = (size_t)bh * (D_*T_);
  u32* pw = sP[wave];

  int srow[2], sdst[2], scolb[2];
  #pragma unroll
  for (int iss = 0; iss < 2; ++iss) {
    int oo = (iss*256 + tid)*16;
    srow[iss]  = oo >> 7;
    scolb[iss] = oo & 127;
    sdst[iss]  = (srow[iss]<<7) | (scolb[iss] ^ ((srow[iss]&7)<<4));
  }
  bf16x8 kreg[2], vreg[2];
  #pragma unroll
  for (int iss = 0; iss < 2; ++iss) {
    kreg[iss] = *(const bf16x8*)((const char*)(Kb + kbase + (size_t)srow[iss]*D_) + scolb[iss]);
    vreg[iss] = *(const bf16x8*)((const char*)(Vb + vbase + (size_t)srow[iss]*T_) + scolb[iss]);
  }

  for (int kt = 0; kt < T_/64; ++kt) {
    __syncthreads();
    #pragma unroll
    for (int iss = 0; iss < 2; ++iss) {
      *(bf16x8*)((char*)sK + sdst[iss]) = kreg[iss];
      *(bf16x8*)((char*)sV + sdst[iss]) = vreg[iss];
    }
    if (kt + 1 < T_/64) {
      #pragma unroll
      for (int iss = 0; iss < 2; ++iss) {
        kreg[iss] = *(const bf16x8*)((const char*)(Kb + kbase + (size_t)((kt+1)*64+srow[iss])*D_) + scolb[iss]);
        vreg[iss] = *(const bf16x8*)((const char*)(Vb + vbase + (size_t)srow[iss]*T_ + (kt+1)*64) + scolb[iss]);
      }
    }
    __syncthreads();

    f32x4 s[2][4];
    #pragma unroll
    for (int mf = 0; mf < 2; ++mf)
      #pragma unroll
      for (int nf = 0; nf < 4; ++nf) s[mf][nf] = (f32x4){0.f,0.f,0.f,0.f};
    __builtin_amdgcn_s_setprio(1);
    #pragma unroll
    for (int nf = 0; nf < 4; ++nf) {
      #pragma unroll
      for (int kc = 0; kc < 2; ++kc) {
        int row = nf*16 + l15;
        int off = (row<<7) | (((kc*64) + l16*16) ^ ((row&7)<<4));
        bf16x8 kf = *(const bf16x8*)((const char*)sK + off);
        s[0][nf] = __builtin_amdgcn_mfma_f32_16x16x32_bf16(kf, qh[0][kc], s[0][nf],0,0,0);
        s[1][nf] = __builtin_amdgcn_mfma_f32_16x16x32_bf16(kf, qh[1][kc], s[1][nf],0,0,0);
      }
    }
    __builtin_amdgcn_s_setprio(0);

    #pragma unroll
    for (int mf = 0; mf < 2; ++mf) {
      int q = mf*16 + l15;
      u32* prow = pw + q*32;
      int swz = (q & 7) << 2;
      #pragma unroll
      for (int nf = 0; nf < 4; ++nf) {
        float p0 = __builtin_amdgcn_exp2f(s[mf][nf][0]);
        float p1 = __builtin_amdgcn_exp2f(s[mf][nf][1]);
        float p2 = __builtin_amdgcn_exp2f(s[mf][nf][2]);
        float p3 = __builtin_amdgcn_exp2f(s[mf][nf][3]);
        l_r[mf] += (p0 + p1) + (p2 + p3);
        u32x2 w2;
        w2[0] = pack2bf(p0, p1);
        w2[1] = pack2bf(p2, p3);
        *(u32x2*)(prow + ((8*nf + 2*l16) ^ swz)) = w2;
      }
    }

    __builtin_amdgcn_s_setprio(1);
    #pragma unroll
    for (int kc = 0; kc < 2; ++kc) {
      bf16x8 pf[2];
      #pragma unroll
      for (int mf = 0; mf < 2; ++mf) {
        int q = mf*16 + l15;
        pf[mf] = *(const bf16x8*)(pw + q*32 + ((kc*16 + l16*4) ^ ((q&7)<<2)));
      }
      #pragma unroll
      for (int df = 0; df < 4; ++df) {
        int row = df*16 + l15;
        int offv = (row<<7) | (((kc*64) + l16*16) ^ ((row&7)<<4));
        bf16x8 vf = *(const bf16x8*)((const char*)sV + offv);
        o[0][df] = __builtin_amdgcn_mfma_f32_16x16x32_bf16(pf[0], vf, o[0][df],0,0,0);
        o[1][df] = __builtin_amdgcn_mfma_f32_16x16x32_bf16(pf[1], vf, o[1][df],0,0,0);
      }
    }
    __builtin_amdgcn_s_setprio(0);
  }

  #pragma unroll
  for (int mf = 0; mf < 2; ++mf) {
    float t = l_r[mf];
    t += __shfl_xor(t, 16);
    t += __shfl_xor(t, 32);
    l_r[mf] = t;
  }

  const int b = bh / H_, h = bh % H_;
  #pragma unroll
  for (int mf = 0; mf < 2; ++mf)
    #pragma unroll
    for (int r = 0; r < 4; ++r) {
      float inv = 1.0f / __shfl(l_r[mf], (l16 << 2) + r);
      int t = q0 + mf*16 + l16*4 + r;
      size_t rowb = ((size_t)(b*T_ + t))*C_ + h*D_;
      #pragma unroll
      for (int df = 0; df < 4; ++df)
        AOb[rowb + df*16 + l15] = f2bf(o[mf][df][r] * inv);
    }
}

extern "C" void kernel_launch(void* const* d_in, const int* in_sizes, int n_in,
                              void* d_out, int out_size, void* d_ws, size_t ws_size,
                              hipStream_t stream) {
  const float* X  = (const float*)d_in[0];
  const float* qw = (const float*)d_in[1];
  const float* qb = (const float*)d_in[2];
  const float* kw = (const float*)d_in[3];
  const float* kb = (const float*)d_in[4];
  const float* vw = (const float*)d_in[5];
  const float* vb = (const float*)d_in[6];
  const float* ow = (const float*)d_in[7];
  const float* ob = (const float*)d_in[8];
  float* out = (float*)d_out;

  const size_t SZ = (size_t)BT_*C_*sizeof(u16);   // 50,331,648 B per buffer
  const size_t NEED = 4*SZ + 5*(size_t)CC_*sizeof(u16);  // +5.9 MB weights
  if (ws_size < NEED) {
    sentinel_kernel<<<(out_size+255)/256,256,0,stream>>>(out, out_size);
    return;
  }
  char* ws = (char*)d_ws;
  u16* Qb   = (u16*)(ws + 0*SZ);
  u16* Kb   = (u16*)(ws + 1*SZ);
  u16* Vb   = (u16*)(ws + 2*SZ);
  u16* AOb  = (u16*)(ws + 3*SZ);
  u16* W3b  = (u16*)(ws + 4*SZ);
  u16* Wohi = W3b + 3*(size_t)CC_;
  u16* Wolo = Wohi + (size_t)CC_;
  u16* Xb   = AOb;   // X-bf16 lives in the AO slot until attn overwrites it

  wquant_kernel<<<CC_/4/256,256,0,stream>>>(qw, kw, vw, ow, W3b, Wohi, Wolo);
  xquant_kernel<<<2048,256,0,stream>>>(X, Xb, BT_*C_/8);
  gemm_qkv<<<1152,512,0,stream>>>(Xb, W3b, qb, kb, vb, Qb, Kb, Vb);
  attn_kernel<<<3072,256,0,stream>>>(Qb, Kb, Vb, AOb);
  gemm_out<<<1536,256,0,stream>>>(AOb, Wohi, Wolo, ob, out);
}

// Round 12
// 337.335 us; speedup vs baseline: 1.1562x; 1.1562x over previous
//
#include <hip/hip_runtime.h>
#include <hip/hip_bf16.h>

#define B_ 32
#define T_ 1024
#define C_ 768
#define H_ 12
#define D_ 64
#define BT_ (B_*T_)
#define CC_ (C_*C_)

typedef __attribute__((ext_vector_type(4))) float f32x4;
typedef __attribute__((ext_vector_type(8))) short bf16x8;
typedef __attribute__((ext_vector_type(4))) short short4_t;
typedef __attribute__((ext_vector_type(2))) unsigned int u32x2;
typedef unsigned short u16;
typedef unsigned int u32;

// Q pre-scale: 1/sqrt(64) * log2(e), so attention probs = exp2(score).
#define QSCALE 0.1803368801111244f

__device__ __forceinline__ float bf2f(u16 u){
  union { float f; unsigned int i; } v; v.i = ((unsigned int)u)<<16; return v.f;
}
__device__ __forceinline__ u16 f2bf(float f){
  union { float f; unsigned int i; } v; v.f = f;
  return (u16)((v.i + 0x7fffu + ((v.i>>16)&1u)) >> 16);
}
// pack two positive floats to bf16 pair (round-half-up), lo in bits[15:0]
__device__ __forceinline__ u32 pack2bf(float lo, float hi){
  union { float f; u32 i; } a, b; a.f = lo; b.f = hi;
  return ((a.i + 0x8000u) >> 16) | ((b.i + 0x8000u) & 0xFFFF0000u);
}
__device__ __forceinline__ void split2(float f, u16& h, u16& l){
  h = f2bf(f);
  l = f2bf(f - bf2f(h));
}

// global -> LDS direct copy, 16B per lane; LDS dest = base + lane*16 (linear).
__device__ __forceinline__ void gll16(const void* g, void* l){
  __builtin_amdgcn_global_load_lds(
      (const __attribute__((address_space(1))) u32*)g,
      (__attribute__((address_space(3))) u32*)l, 16, 0, 0);
}

__global__ void sentinel_kernel(float* out, int n){
  int i = blockIdx.x*blockDim.x + threadIdx.x;
  if (i < n) out[i] = 12345.0f;
}

// fp32 -> bf16, 8 elements/thread
__global__ void xquant_kernel(const float* __restrict__ x, u16* __restrict__ xb, int n8){
  int i = blockIdx.x*blockDim.x + threadIdx.x;
  int stride = gridDim.x*blockDim.x;
  for (; i < n8; i += stride) {
    f32x4 a = *(const f32x4*)(x + (size_t)i*8);
    f32x4 b = *(const f32x4*)(x + (size_t)i*8 + 4);
    bf16x8 o;
    #pragma unroll
    for (int j = 0; j < 4; ++j) { o[j] = (short)f2bf(a[j]); o[j+4] = (short)f2bf(b[j]); }
    *(bf16x8*)(xb + (size_t)i*8) = o;
  }
}

// One-shot weight prep: qw/kw/vw -> bf16 concat W3b; ow -> bf16 Wob.
__global__ void wquant_kernel(const float* __restrict__ qw, const float* __restrict__ kw,
                              const float* __restrict__ vw, const float* __restrict__ ow,
                              u16* __restrict__ W3b, u16* __restrict__ Wob){
  int i = (blockIdx.x*blockDim.x + threadIdx.x)*4;
  if (i >= CC_) return;
  f32x4 q = *(const f32x4*)(qw+i);
  f32x4 k = *(const f32x4*)(kw+i);
  f32x4 v = *(const f32x4*)(vw+i);
  f32x4 o = *(const f32x4*)(ow+i);
  short4_t tq, tk, tv, to;
  #pragma unroll
  for (int j = 0; j < 4; ++j) {
    tq[j] = (short)f2bf(q[j]);
    tk[j] = (short)f2bf(k[j]);
    tv[j] = (short)f2bf(v[j]);
    to[j] = (short)f2bf(o[j]);
  }
  *(short4_t*)(W3b + i)          = tq;
  *(short4_t*)(W3b + CC_ + i)    = tk;
  *(short4_t*)(W3b + 2*CC_ + i)  = tv;
  *(short4_t*)(Wob + i)          = to;
}

// QKV projection (r8-verified 128x128 m97-structure kernel, 853 TF):
// global_load_lds width-16 staging, linear LDS [128][64] with XOR-swizzled
// global source (col16 ^= row&7) + matching XOR on fragment reads.
// z=0: Q*QSCALE -> (B,H,T,D); z=1: K -> (B,H,T,D); z=2: V -> (B,H,D,T).
// Grid 4608 = 8 XCDs x (32 mloc x 6 nb x 3 z), z/n innermost.
__global__ __launch_bounds__(256,2)
void gemm_qkv(const u16* __restrict__ Ab, const u16* __restrict__ Wb,
              const float* __restrict__ bq, const float* __restrict__ bk,
              const float* __restrict__ bv,
              u16* __restrict__ Qb, u16* __restrict__ Kb, u16* __restrict__ Vb)
{
  __shared__ __align__(1024) u16 sA[128*64];
  __shared__ __align__(1024) u16 sB[128*64];
  const int tid = threadIdx.x;
  const int lane = tid & 63;
  const int l15 = lane & 15, l16 = lane >> 4;
  const int wave = tid >> 6;
  const int wr = wave >> 1, wc = wave & 1;

  const int bid = blockIdx.x;
  const int xcd = bid & 7;
  const int idx = bid >> 3;
  const int z = idx % 3;
  const int r_ = idx / 3;
  const int nb = r_ % 6, mloc = r_ / 6;
  const int m0 = (xcd*32 + mloc) * 128;
  const int n0 = nb * 128;
  const u16* W = Wb + (size_t)z*CC_;
  const float* bias = (z==0) ? bq : (z==1 ? bk : bv);

  const int lrow = lane >> 3;
  const int cbyte = ((lane & 7) ^ lrow) << 4;

  f32x4 acc[4][4];
  #pragma unroll
  for (int i=0;i<4;++i)
    #pragma unroll
    for (int j=0;j<4;++j)
      acc[i][j] = (f32x4){0.f,0.f,0.f,0.f};

  for (int k0 = 0; k0 < C_; k0 += 64) {
    __syncthreads();
    #pragma unroll
    for (int sg = 0; sg < 4; ++sg) {
      int seg = wave*4 + sg;
      int row = seg*8 + lrow;
      gll16((const char*)(Ab + (size_t)(m0+row)*C_ + k0) + cbyte, sA + seg*512);
      gll16((const char*)(W  + (size_t)(n0+row)*C_ + k0) + cbyte, sB + seg*512);
    }
    asm volatile("s_waitcnt vmcnt(0)" ::: "memory");
    __syncthreads();

    #pragma unroll
    for (int kc = 0; kc < 2; ++kc) {
      bf16x8 a[4], bh[4];
      #pragma unroll
      for (int mf = 0; mf < 4; ++mf) {
        int row = wr*64 + mf*16 + l15;
        int off = (row<<7) + ((kc*64 + l16*16) ^ ((row&7)<<4));
        a[mf] = *(const bf16x8*)((const char*)sA + off);
      }
      #pragma unroll
      for (int nf = 0; nf < 4; ++nf) {
        int row = wc*64 + nf*16 + l15;
        int off = (row<<7) + ((kc*64 + l16*16) ^ ((row&7)<<4));
        bh[nf] = *(const bf16x8*)((const char*)sB + off);
      }
      #pragma unroll
      for (int mf = 0; mf < 4; ++mf)
        #pragma unroll
        for (int nf = 0; nf < 4; ++nf)
          acc[mf][nf] = __builtin_amdgcn_mfma_f32_16x16x32_bf16(a[mf], bh[nf], acc[mf][nf],0,0,0);
    }
  }

  #pragma unroll
  for (int mf = 0; mf < 4; ++mf) {
    #pragma unroll
    for (int nf = 0; nf < 4; ++nf) {
      int mgb = m0 + wr*64 + mf*16 + l16*4;
      int ng  = n0 + wc*64 + nf*16 + l15;
      float bv = bias[ng];
      int b = mgb >> 10, t0 = mgb & 1023;
      int h = ng >> 6, d = ng & 63;
      int bh_ = b*H_ + h;
      if (z == 2) {
        short4_t vh;
        #pragma unroll
        for (int r = 0; r < 4; ++r)
          vh[r] = (short)f2bf(acc[mf][nf][r] + bv);
        size_t idx2 = ((size_t)bh_*D_ + d)*T_ + t0;
        *(short4_t*)&Vb[idx2] = vh;
      } else {
        u16* dst = (z==0) ? Qb : Kb;
        float scale = (z==0) ? QSCALE : 1.0f;
        #pragma unroll
        for (int r = 0; r < 4; ++r) {
          size_t idx2 = ((size_t)bh_*T_ + (t0+r))*D_ + d;
          dst[idx2] = f2bf((acc[mf][nf][r] + bv) * scale);
        }
      }
    }
  }
}

// O-projection, single-pass bf16 (W quantization error ~1e-3 RMS tolerated by
// the 8.16e-3 threshold; revert to hi/lo 2-pass if absmax exceeds).
// Same m97 structure, 32 KB LDS.
__global__ __launch_bounds__(256,2)
void gemm_out(const u16* __restrict__ Ab, const u16* __restrict__ Wb,
              const float* __restrict__ bo, float* __restrict__ Out)
{
  __shared__ __align__(1024) u16 sA[128*64];
  __shared__ __align__(1024) u16 sB[128*64];
  const int tid = threadIdx.x;
  const int lane = tid & 63;
  const int l15 = lane & 15, l16 = lane >> 4;
  const int wave = tid >> 6;
  const int wr = wave >> 1, wc = wave & 1;

  const int bid = blockIdx.x;
  const int xcd = bid & 7;
  const int idx = bid >> 3;
  const int nb = idx % 6, mloc = idx / 6;
  const int m0 = (xcd*32 + mloc) * 128;
  const int n0 = nb * 128;

  const int lrow = lane >> 3;
  const int cbyte = ((lane & 7) ^ lrow) << 4;

  f32x4 acc[4][4];
  #pragma unroll
  for (int i=0;i<4;++i)
    #pragma unroll
    for (int j=0;j<4;++j)
      acc[i][j] = (f32x4){0.f,0.f,0.f,0.f};

  for (int k0 = 0; k0 < C_; k0 += 64) {
    __syncthreads();
    #pragma unroll
    for (int sg = 0; sg < 4; ++sg) {
      int seg = wave*4 + sg;
      int row = seg*8 + lrow;
      gll16((const char*)(Ab + (size_t)(m0+row)*C_ + k0) + cbyte, sA + seg*512);
      gll16((const char*)(Wb + (size_t)(n0+row)*C_ + k0) + cbyte, sB + seg*512);
    }
    asm volatile("s_waitcnt vmcnt(0)" ::: "memory");
    __syncthreads();

    #pragma unroll
    for (int kc = 0; kc < 2; ++kc) {
      bf16x8 a[4], bh[4];
      #pragma unroll
      for (int mf = 0; mf < 4; ++mf) {
        int row = wr*64 + mf*16 + l15;
        int off = (row<<7) + ((kc*64 + l16*16) ^ ((row&7)<<4));
        a[mf] = *(const bf16x8*)((const char*)sA + off);
      }
      #pragma unroll
      for (int nf = 0; nf < 4; ++nf) {
        int row = wc*64 + nf*16 + l15;
        int off = (row<<7) + ((kc*64 + l16*16) ^ ((row&7)<<4));
        bh[nf] = *(const bf16x8*)((const char*)sB + off);
      }
      #pragma unroll
      for (int mf = 0; mf < 4; ++mf)
        #pragma unroll
        for (int nf = 0; nf < 4; ++nf)
          acc[mf][nf] = __builtin_amdgcn_mfma_f32_16x16x32_bf16(a[mf], bh[nf], acc[mf][nf],0,0,0);
    }
  }

  #pragma unroll
  for (int mf = 0; mf < 4; ++mf) {
    #pragma unroll
    for (int nf = 0; nf < 4; ++nf) {
      int mgb = m0 + wr*64 + mf*16 + l16*4;
      int ng  = n0 + wc*64 + nf*16 + l15;
      float bv = bo[ng];
      #pragma unroll
      for (int r = 0; r < 4; ++r)
        Out[(size_t)(mgb+r)*C_ + ng] = acc[mf][nf][r] + bv;
    }
  }
}

// Flash attention, no-max softmax. SWAPPED QK^T: s = mfma(K_frag, Q_frag) so
// lane holds P^T: q = lane&15, key = 16nf + (lane>>4)*4 + r. Rowsum is
// lane-local. P regroup via per-wave LDS bounce (8x ds_write_b64, swizzled).
// One workgroup = (b,h) x 128 q-rows; 4 waves x 32 rows (2 m-frags).
// T14 async-stage K/V via register prefetch. Grid 3072 XCD-swizzled.
__global__ __launch_bounds__(256,2)
void attn_kernel(const u16* __restrict__ Qb, const u16* __restrict__ Kb,
                 const u16* __restrict__ Vb, u16* __restrict__ AOb)
{
  __shared__ __align__(16) u16 sK[64*64];
  __shared__ __align__(16) u16 sV[64*64];   // [d][key]
  __shared__ __align__(16) u32 sP[4][32*32]; // per wave: [q 32][key-word 32]
  const int tid = threadIdx.x;
  const int lane = tid & 63;
  const int l15 = lane & 15, l16 = lane >> 4;
  const int wave = tid >> 6;
  const int bid = blockIdx.x;
  const int sw  = (bid & 7) * 384 + (bid >> 3);   // 3072 = 8 XCDs * 384
  const int bh  = sw >> 3;
  const int q0  = (sw & 7) * 128 + wave * 32;

  bf16x8 qh[2][2];
  #pragma unroll
  for (int mf = 0; mf < 2; ++mf)
    #pragma unroll
    for (int kc = 0; kc < 2; ++kc)
      qh[mf][kc] = *(const bf16x8*)(Qb + ((size_t)bh*T_ + q0 + mf*16 + l15)*D_ + kc*32 + l16*8);

  f32x4 o[2][4];
  #pragma unroll
  for (int mf = 0; mf < 2; ++mf)
    #pragma unroll
    for (int i = 0; i < 4; ++i) o[mf][i] = (f32x4){0.f,0.f,0.f,0.f};
  float l_r[2] = {0.f, 0.f};

  const size_t kbase = (size_t)bh * (T_*D_);
  const size_t vbase = (size_t)bh * (D_*T_);
  u32* pw = sP[wave];

  int srow[2], sdst[2], scolb[2];
  #pragma unroll
  for (int iss = 0; iss < 2; ++iss) {
    int oo = (iss*256 + tid)*16;
    srow[iss]  = oo >> 7;
    scolb[iss] = oo & 127;
    sdst[iss]  = (srow[iss]<<7) | (scolb[iss] ^ ((srow[iss]&7)<<4));
  }
  bf16x8 kreg[2], vreg[2];
  #pragma unroll
  for (int iss = 0; iss < 2; ++iss) {
    kreg[iss] = *(const bf16x8*)((const char*)(Kb + kbase + (size_t)srow[iss]*D_) + scolb[iss]);
    vreg[iss] = *(const bf16x8*)((const char*)(Vb + vbase + (size_t)srow[iss]*T_) + scolb[iss]);
  }

  for (int kt = 0; kt < T_/64; ++kt) {
    __syncthreads();
    #pragma unroll
    for (int iss = 0; iss < 2; ++iss) {
      *(bf16x8*)((char*)sK + sdst[iss]) = kreg[iss];
      *(bf16x8*)((char*)sV + sdst[iss]) = vreg[iss];
    }
    if (kt + 1 < T_/64) {
      #pragma unroll
      for (int iss = 0; iss < 2; ++iss) {
        kreg[iss] = *(const bf16x8*)((const char*)(Kb + kbase + (size_t)((kt+1)*64+srow[iss])*D_) + scolb[iss]);
        vreg[iss] = *(const bf16x8*)((const char*)(Vb + vbase + (size_t)srow[iss]*T_ + (kt+1)*64) + scolb[iss]);
      }
    }
    __syncthreads();

    f32x4 s[2][4];
    #pragma unroll
    for (int mf = 0; mf < 2; ++mf)
      #pragma unroll
      for (int nf = 0; nf < 4; ++nf) s[mf][nf] = (f32x4){0.f,0.f,0.f,0.f};
    __builtin_amdgcn_s_setprio(1);
    #pragma unroll
    for (int nf = 0; nf < 4; ++nf) {
      #pragma unroll
      for (int kc = 0; kc < 2; ++kc) {
        int row = nf*16 + l15;
        int off = (row<<7) | (((kc*64) + l16*16) ^ ((row&7)<<4));
        bf16x8 kf = *(const bf16x8*)((const char*)sK + off);
        s[0][nf] = __builtin_amdgcn_mfma_f32_16x16x32_bf16(kf, qh[0][kc], s[0][nf],0,0,0);
        s[1][nf] = __builtin_amdgcn_mfma_f32_16x16x32_bf16(kf, qh[1][kc], s[1][nf],0,0,0);
      }
    }
    __builtin_amdgcn_s_setprio(0);

    #pragma unroll
    for (int mf = 0; mf < 2; ++mf) {
      int q = mf*16 + l15;
      u32* prow = pw + q*32;
      int swz = (q & 7) << 2;
      #pragma unroll
      for (int nf = 0; nf < 4; ++nf) {
        float p0 = __builtin_amdgcn_exp2f(s[mf][nf][0]);
        float p1 = __builtin_amdgcn_exp2f(s[mf][nf][1]);
        float p2 = __builtin_amdgcn_exp2f(s[mf][nf][2]);
        float p3 = __builtin_amdgcn_exp2f(s[mf][nf][3]);
        l_r[mf] += (p0 + p1) + (p2 + p3);
        u32x2 w2;
        w2[0] = pack2bf(p0, p1);
        w2[1] = pack2bf(p2, p3);
        *(u32x2*)(prow + ((8*nf + 2*l16) ^ swz)) = w2;
      }
    }

    __builtin_amdgcn_s_setprio(1);
    #pragma unroll
    for (int kc = 0; kc < 2; ++kc) {
      bf16x8 pf[2];
      #pragma unroll
      for (int mf = 0; mf < 2; ++mf) {
        int q = mf*16 + l15;
        pf[mf] = *(const bf16x8*)(pw + q*32 + ((kc*16 + l16*4) ^ ((q&7)<<2)));
      }
      #pragma unroll
      for (int df = 0; df < 4; ++df) {
        int row = df*16 + l15;
        int offv = (row<<7) | (((kc*64) + l16*16) ^ ((row&7)<<4));
        bf16x8 vf = *(const bf16x8*)((const char*)sV + offv);
        o[0][df] = __builtin_amdgcn_mfma_f32_16x16x32_bf16(pf[0], vf, o[0][df],0,0,0);
        o[1][df] = __builtin_amdgcn_mfma_f32_16x16x32_bf16(pf[1], vf, o[1][df],0,0,0);
      }
    }
    __builtin_amdgcn_s_setprio(0);
  }

  #pragma unroll
  for (int mf = 0; mf < 2; ++mf) {
    float t = l_r[mf];
    t += __shfl_xor(t, 16);
    t += __shfl_xor(t, 32);
    l_r[mf] = t;
  }

  const int b = bh / H_, h = bh % H_;
  #pragma unroll
  for (int mf = 0; mf < 2; ++mf)
    #pragma unroll
    for (int r = 0; r < 4; ++r) {
      float inv = 1.0f / __shfl(l_r[mf], (l16 << 2) + r);
      int t = q0 + mf*16 + l16*4 + r;
      size_t rowb = ((size_t)(b*T_ + t))*C_ + h*D_;
      #pragma unroll
      for (int df = 0; df < 4; ++df)
        AOb[rowb + df*16 + l15] = f2bf(o[mf][df][r] * inv);
    }
}

extern "C" void kernel_launch(void* const* d_in, const int* in_sizes, int n_in,
                              void* d_out, int out_size, void* d_ws, size_t ws_size,
                              hipStream_t stream) {
  const float* X  = (const float*)d_in[0];
  const float* qw = (const float*)d_in[1];
  const float* qb = (const float*)d_in[2];
  const float* kw = (const float*)d_in[3];
  const float* kb = (const float*)d_in[4];
  const float* vw = (const float*)d_in[5];
  const float* vb = (const float*)d_in[6];
  const float* ow = (const float*)d_in[7];
  const float* ob = (const float*)d_in[8];
  float* out = (float*)d_out;

  const size_t SZ = (size_t)BT_*C_*sizeof(u16);   // 50,331,648 B per buffer
  const size_t NEED = 4*SZ + 4*(size_t)CC_*sizeof(u16);
  if (ws_size < NEED) {
    sentinel_kernel<<<(out_size+255)/256,256,0,stream>>>(out, out_size);
    return;
  }
  char* ws = (char*)d_ws;
  u16* Qb   = (u16*)(ws + 0*SZ);
  u16* Kb   = (u16*)(ws + 1*SZ);
  u16* Vb   = (u16*)(ws + 2*SZ);
  u16* AOb  = (u16*)(ws + 3*SZ);
  u16* W3b  = (u16*)(ws + 4*SZ);
  u16* Wob  = W3b + 3*(size_t)CC_;
  u16* Xb   = AOb;   // X-bf16 lives in the AO slot until attn overwrites it

  wquant_kernel<<<CC_/4/256,256,0,stream>>>(qw, kw, vw, ow, W3b, Wob);
  xquant_kernel<<<2048,256,0,stream>>>(X, Xb, BT_*C_/8);
  gemm_qkv<<<4608,256,0,stream>>>(Xb, W3b, qb, kb, vb, Qb, Kb, Vb);
  attn_kernel<<<3072,256,0,stream>>>(Qb, Kb, Vb, AOb);
  gemm_out<<<1536,256,0,stream>>>(AOb, Wob, ob, out);
}